// Round 9
// baseline (221.885 us; speedup 1.0000x reference)
//
#include <hip/hip_runtime.h>

// out = L@(X@W1 + X^2@W2) + X@W1 + b1 + b2
// Y (bf16, ws) = X@W1 + X^2@W2 ; Z = X@W1 + b1 + b2 (-> out).
// Round 9: fused_nt_bin with k-staged W (union LDS 33 KB -> 4 blocks/CU);
// gather split by ROW-half (full-64-feature, full-line Y reads, direct
// sorted placement, overflow drain folded in). 3 dispatches total.

#define ROWS_PER_BUCKET 128
#define ROW_SHIFT 7
#define NBUCK_PAD 784        // 196*4, covers nbuck=782
#define SCAN_T 196
#define CAP 2048             // per-bucket fixed capacity (mean 1536, +13 sigma)
#define CHUNK 2048           // edges per scatter-role block
#define NT_ROWS 64           // rows per transform-role block
#define KSTEP 16             // k-slice of W staged at a time
#define COL_BITS 17
#define COL_MASK 0x1FFFF
#define OVF_CAP 65536

__device__ __forceinline__ unsigned short f2bf(float x) {
    unsigned u = __float_as_uint(x);
    unsigned r = (u + 0x7FFFu + ((u >> 16) & 1u)) >> 16;   // RNE
    return (unsigned short)r;
}
__device__ __forceinline__ float bf2f(unsigned short h) {
    return __uint_as_float(((unsigned)h) << 16);
}

struct ScatterSmem {                 // ~33 KB
    int lcount[NBUCK_PAD];
    int lstart[NBUCK_PAD];
    int lcursor[NBUCK_PAD];
    int gbase[NBUCK_PAD];
    int sx[CHUNK];
    int sy[CHUNK];
    unsigned short sbk[CHUNK];
};
struct NtSmem {                      // ~25.2 KB (k-staged W)
    float W1s[KSTEP * 64];
    float W2s[KSTEP * 64];
    float xs[NT_ROWS][65];
    float bs[64];
};
union FusedSmem { ScatterSmem s; NtSmem n; };

__global__ __launch_bounds__(256) void cursor_init(
    int* __restrict__ gcursor, int* __restrict__ ovf_count, int nbp) {
    int i = blockIdx.x * 256 + threadIdx.x;
    if (i < nbp) gcursor[i] = i * CAP;
    if (i == 0) *ovf_count = 0;
}

__global__ __launch_bounds__(256) void fused_nt_bin(
    const float* __restrict__ X, const float* __restrict__ W1,
    const float* __restrict__ b1, const float* __restrict__ W2,
    const float* __restrict__ b2, unsigned short* __restrict__ Yb,
    float* __restrict__ Z,
    const int* __restrict__ rows, const int* __restrict__ cols,
    const float* __restrict__ vals, int* __restrict__ gcursor,
    int2* __restrict__ packed, int* __restrict__ ovf_count,
    int4* __restrict__ ovf, int n_nodes, int n_edges, int eb)
{
    __shared__ FusedSmem u;
    const int tid = threadIdx.x;

    if ((int)blockIdx.x < eb) {
        // ---------------- scatter role ----------------
        int eb0 = blockIdx.x * CHUNK;
        int cnt = min(CHUNK, n_edges - eb0);

        for (int k = tid; k < NBUCK_PAD; k += 256) u.s.lcount[k] = 0;
        __syncthreads();

        for (int i = tid; i < cnt; i += 256)
            atomicAdd(&u.s.lcount[rows[eb0 + i] >> ROW_SHIFT], 1);
        __syncthreads();

        // exclusive scan of lcount: thread t<SCAN_T owns 4t..4t+3
        int c0 = 0, c1 = 0, c2 = 0, c3 = 0, psum = 0;
        if (tid < SCAN_T) {
            c0 = u.s.lcount[tid * 4 + 0]; c1 = u.s.lcount[tid * 4 + 1];
            c2 = u.s.lcount[tid * 4 + 2]; c3 = u.s.lcount[tid * 4 + 3];
            psum = c0 + c1 + c2 + c3;
        }
        u.s.sx[tid] = psum;
        __syncthreads();
#pragma unroll
        for (int o = 1; o < 256; o <<= 1) {
            int t = (tid >= o) ? u.s.sx[tid - o] : 0;
            __syncthreads();
            u.s.sx[tid] += t;
            __syncthreads();
        }
        int base0 = u.s.sx[tid] - psum;
        __syncthreads();
        if (tid < SCAN_T) {
            u.s.lstart[tid * 4 + 0] = base0;
            u.s.lstart[tid * 4 + 1] = base0 + c0;
            u.s.lstart[tid * 4 + 2] = base0 + c0 + c1;
            u.s.lstart[tid * 4 + 3] = base0 + c0 + c1 + c2;
        }
        __syncthreads();

        for (int k = tid; k < NBUCK_PAD; k += 256) {
            u.s.lcursor[k] = u.s.lstart[k];
            if (u.s.lcount[k] > 0)
                u.s.gbase[k] = atomicAdd(&gcursor[k], u.s.lcount[k]);
        }
        __syncthreads();

        for (int i = tid; i < cnt; i += 256) {
            int r = rows[eb0 + i];
            int b = r >> ROW_SHIFT;
            int p = atomicAdd(&u.s.lcursor[b], 1);
            u.s.sx[p] = ((r & (ROWS_PER_BUCKET - 1)) << COL_BITS) | cols[eb0 + i];
            u.s.sy[p] = __float_as_int(vals[eb0 + i]);
            u.s.sbk[p] = (unsigned short)b;
        }
        __syncthreads();

        for (int i = tid; i < cnt; i += 256) {
            int b = u.s.sbk[i];
            int dest = u.s.gbase[b] + (i - u.s.lstart[b]);
            if (dest < (b + 1) * CAP) {
                packed[dest] = make_int2(u.s.sx[i], u.s.sy[i]);
            } else {
                int p = atomicAdd(ovf_count, 1);
                if (p < OVF_CAP)
                    ovf[p] = make_int4(
                        b * ROWS_PER_BUCKET + (u.s.sx[i] >> COL_BITS),
                        u.s.sx[i] & COL_MASK, u.s.sy[i], 0);
            }
        }
    } else {
        // ------------- transform role (64-row tile, k-staged W) -------------
        const int base = (blockIdx.x - eb) * NT_ROWS;

        if (tid < 64) u.n.bs[tid] = b1[tid] + b2[tid];
        {
#pragma unroll
            for (int i = 0; i < 4; ++i) {
                int idx = (tid + 256 * i) * 4;
                int r = idx >> 6, c = idx & 63;
                if (base + r < n_nodes) {
                    float4 v = *(const float4*)(X + (size_t)base * 64 + idx);
                    u.n.xs[r][c + 0] = v.x; u.n.xs[r][c + 1] = v.y;
                    u.n.xs[r][c + 2] = v.z; u.n.xs[r][c + 3] = v.w;
                }
            }
        }

        const int tx = tid & 7;    // features 8*tx..8*tx+7
        const int ty = tid >> 3;   // rows 2*ty, 2*ty+1

        float acc1[2][8] = {};
        float acc2[2][8] = {};

        for (int ks = 0; ks < 64; ks += KSTEP) {
            __syncthreads();   // also covers xs/bs on first pass; W reuse after
            // stage W slice: KSTEP*64 floats each = 256 float4 -> 1/thread
            {
                const float4* w1v = (const float4*)(W1 + ks * 64);
                const float4* w2v = (const float4*)(W2 + ks * 64);
                ((float4*)u.n.W1s)[tid] = w1v[tid];
                ((float4*)u.n.W2s)[tid] = w2v[tid];
            }
            __syncthreads();

#pragma unroll
            for (int kk = 0; kk < KSTEP; ++kk) {
                float4 wa0 = *(const float4*)(u.n.W1s + kk * 64 + tx * 8);
                float4 wa1 = *(const float4*)(u.n.W1s + kk * 64 + tx * 8 + 4);
                float4 wb0 = *(const float4*)(u.n.W2s + kk * 64 + tx * 8);
                float4 wb1 = *(const float4*)(u.n.W2s + kk * 64 + tx * 8 + 4);
#pragma unroll
                for (int i = 0; i < 2; ++i) {
                    float xv = u.n.xs[ty * 2 + i][ks + kk];
                    float xq = xv * xv;
                    acc1[i][0] = fmaf(xv, wa0.x, acc1[i][0]);
                    acc1[i][1] = fmaf(xv, wa0.y, acc1[i][1]);
                    acc1[i][2] = fmaf(xv, wa0.z, acc1[i][2]);
                    acc1[i][3] = fmaf(xv, wa0.w, acc1[i][3]);
                    acc1[i][4] = fmaf(xv, wa1.x, acc1[i][4]);
                    acc1[i][5] = fmaf(xv, wa1.y, acc1[i][5]);
                    acc1[i][6] = fmaf(xv, wa1.z, acc1[i][6]);
                    acc1[i][7] = fmaf(xv, wa1.w, acc1[i][7]);
                    acc2[i][0] = fmaf(xq, wb0.x, acc2[i][0]);
                    acc2[i][1] = fmaf(xq, wb0.y, acc2[i][1]);
                    acc2[i][2] = fmaf(xq, wb0.z, acc2[i][2]);
                    acc2[i][3] = fmaf(xq, wb0.w, acc2[i][3]);
                    acc2[i][4] = fmaf(xq, wb1.x, acc2[i][4]);
                    acc2[i][5] = fmaf(xq, wb1.y, acc2[i][5]);
                    acc2[i][6] = fmaf(xq, wb1.z, acc2[i][6]);
                    acc2[i][7] = fmaf(xq, wb1.w, acc2[i][7]);
                }
            }
        }

        float bv[8];
#pragma unroll
        for (int j = 0; j < 8; ++j) bv[j] = u.n.bs[tx * 8 + j];

#pragma unroll
        for (int i = 0; i < 2; ++i) {
            int node = base + ty * 2 + i;
            if (node < n_nodes) {
                float z[8];
                unsigned pk[4];
#pragma unroll
                for (int j = 0; j < 4; ++j) {
                    float ylo = acc1[i][2 * j]     + acc2[i][2 * j];
                    float yhi = acc1[i][2 * j + 1] + acc2[i][2 * j + 1];
                    pk[j] = (unsigned)f2bf(ylo) | ((unsigned)f2bf(yhi) << 16);
                }
#pragma unroll
                for (int j = 0; j < 8; ++j) z[j] = acc1[i][j] + bv[j];
                unsigned short* yp = Yb + (size_t)node * 64 + tx * 8;
                float* zp = Z + (size_t)node * 64 + tx * 8;
                *(uint4*)(yp) = make_uint4(pk[0], pk[1], pk[2], pk[3]);
                *(float4*)(zp)     = make_float4(z[0], z[1], z[2], z[3]);
                *(float4*)(zp + 4) = make_float4(z[4], z[5], z[6], z[7]);
            }
        }
    }
}

// 2 blocks per bucket, split by ROW half (64 rows each, all 64 features).
// Direct counting-sort placement into sxy (no index indirection), full-line
// bf16 Y reads, register accumulate, coalesced out+=. Overflow drain at end.
__global__ __launch_bounds__(256) void bucket_gather_half(
    const int* __restrict__ gcursor, const int2* __restrict__ packed,
    const unsigned short* __restrict__ Yb, float* __restrict__ out,
    const int* __restrict__ ovf_count, const int4* __restrict__ ovf,
    int n_nodes) {
    __shared__ int2 sxy[CAP];          // 16 KB
    __shared__ int hist[64];
    __shared__ int chs[64];
    __shared__ int chc[64];

    int tid = threadIdx.x;
    int bucket = blockIdx.x >> 1;
    int half = blockIdx.x & 1;
    int wave = tid >> 6;               // 0..3
    int lane = tid & 63;               // = feature
    int s = bucket * CAP;
    int e = min(gcursor[bucket], s + CAP);
    int cnt = e - s;
    int row0 = bucket * ROWS_PER_BUCKET + half * 64;

    if (tid < 64) hist[tid] = 0;
    __syncthreads();

    // pass 1: histogram of my half's rows
    for (int i = tid; i < cnt; i += 256) {
        int r7 = packed[s + i].x >> COL_BITS;
        if ((r7 >> 6) == half) atomicAdd(&hist[r7 & 63], 1);
    }
    __syncthreads();

    // exclusive scan of 64 bins
    if (tid < 64) chs[tid] = hist[tid];
    __syncthreads();
#pragma unroll
    for (int o = 1; o < 64; o <<= 1) {
        int t = 0;
        if (tid < 64 && tid >= o) t = chs[tid - o];
        __syncthreads();
        if (tid < 64) chs[tid] += t;
        __syncthreads();
    }
    if (tid < 64) {
        int excl = chs[tid] - hist[tid];
        chs[tid] = excl;
        chc[tid] = excl;
    }
    __syncthreads();

    // pass 2: place my half's edges row-sorted directly into sxy
    for (int i = tid; i < cnt; i += 256) {
        int2 a = packed[s + i];
        int r7 = a.x >> COL_BITS;
        if ((r7 >> 6) == half) {
            int p = atomicAdd(&chc[r7 & 63], 1);
            sxy[p] = a;
        }
    }
    __syncthreads();

    // register-accumulated gather: wave handles 16 rows, lane = feature
    for (int rr = 0; rr < 16; ++rr) {
        int r = wave * 16 + rr;
        int rc = hist[r];
        int node = row0 + r;
        if (rc == 0 || node >= n_nodes) continue;
        int rs = chs[r];
        float acc = 0.f;
        int j = 0;
        for (; j + 8 <= rc; j += 8) {
            int2 a0 = sxy[rs + j + 0], a1 = sxy[rs + j + 1];
            int2 a2 = sxy[rs + j + 2], a3 = sxy[rs + j + 3];
            int2 a4 = sxy[rs + j + 4], a5 = sxy[rs + j + 5];
            int2 a6 = sxy[rs + j + 6], a7 = sxy[rs + j + 7];
            float f0 = bf2f(Yb[(size_t)(a0.x & COL_MASK) * 64 + lane]);
            float f1 = bf2f(Yb[(size_t)(a1.x & COL_MASK) * 64 + lane]);
            float f2 = bf2f(Yb[(size_t)(a2.x & COL_MASK) * 64 + lane]);
            float f3 = bf2f(Yb[(size_t)(a3.x & COL_MASK) * 64 + lane]);
            float f4 = bf2f(Yb[(size_t)(a4.x & COL_MASK) * 64 + lane]);
            float f5 = bf2f(Yb[(size_t)(a5.x & COL_MASK) * 64 + lane]);
            float f6 = bf2f(Yb[(size_t)(a6.x & COL_MASK) * 64 + lane]);
            float f7 = bf2f(Yb[(size_t)(a7.x & COL_MASK) * 64 + lane]);
            acc = fmaf(__int_as_float(a0.y), f0, acc);
            acc = fmaf(__int_as_float(a1.y), f1, acc);
            acc = fmaf(__int_as_float(a2.y), f2, acc);
            acc = fmaf(__int_as_float(a3.y), f3, acc);
            acc = fmaf(__int_as_float(a4.y), f4, acc);
            acc = fmaf(__int_as_float(a5.y), f5, acc);
            acc = fmaf(__int_as_float(a6.y), f6, acc);
            acc = fmaf(__int_as_float(a7.y), f7, acc);
        }
        for (; j < rc; ++j) {
            int2 a0 = sxy[rs + j];
            acc = fmaf(__int_as_float(a0.y),
                       bf2f(Yb[(size_t)(a0.x & COL_MASK) * 64 + lane]), acc);
        }
        out[(size_t)node * 64 + lane] += acc;   // out holds Z
    }

    // overflow drain (normally empty)
    int oc = min(*ovf_count, OVF_CAP);
    if (oc > 0) {
        long long total = (long long)oc * 64;
        for (long long i = (long long)blockIdx.x * 256 + tid; i < total;
             i += (long long)gridDim.x * 256) {
            int ee = (int)(i >> 6), f = (int)(i & 63);
            int4 a = ovf[ee];
            atomicAdd(&out[(size_t)a.x * 64 + f],
                      __int_as_float(a.z) * bf2f(Yb[(size_t)a.y * 64 + f]));
        }
    }
}

// ---------------- fallback path ----------------

struct FbSmem {
    float W1s[64 * 64];
    float W2s[64 * 64];
    float xs[NT_ROWS][65];
    float bs[64];
};

__global__ __launch_bounds__(256) void node_transform_fb(
    const float* __restrict__ X, const float* __restrict__ W1,
    const float* __restrict__ b1, const float* __restrict__ W2,
    const float* __restrict__ b2, unsigned short* __restrict__ Yb,
    float* __restrict__ Z, int n_nodes)
{
    __shared__ FbSmem n;
    const int tid = threadIdx.x;
    const int base = blockIdx.x * NT_ROWS;
    {
        const float4* w1v = (const float4*)W1;
        const float4* w2v = (const float4*)W2;
        float4* s1 = (float4*)n.W1s;
        float4* s2 = (float4*)n.W2s;
#pragma unroll
        for (int i = 0; i < 4; ++i) {
            s1[tid + 256 * i] = w1v[tid + 256 * i];
            s2[tid + 256 * i] = w2v[tid + 256 * i];
        }
    }
    if (tid < 64) n.bs[tid] = b1[tid] + b2[tid];
#pragma unroll
    for (int i = 0; i < 4; ++i) {
        int idx = (tid + 256 * i) * 4;
        int r = idx >> 6, c = idx & 63;
        if (base + r < n_nodes) {
            float4 v = *(const float4*)(X + (size_t)base * 64 + idx);
            n.xs[r][c + 0] = v.x; n.xs[r][c + 1] = v.y;
            n.xs[r][c + 2] = v.z; n.xs[r][c + 3] = v.w;
        }
    }
    __syncthreads();
    const int tx = tid & 7;
    const int ty = tid >> 3;
    float acc1[2][8] = {};
    float acc2[2][8] = {};
#pragma unroll 2
    for (int k = 0; k < 64; ++k) {
        float4 wa0 = *(const float4*)(n.W1s + k * 64 + tx * 8);
        float4 wa1 = *(const float4*)(n.W1s + k * 64 + tx * 8 + 4);
        float4 wb0 = *(const float4*)(n.W2s + k * 64 + tx * 8);
        float4 wb1 = *(const float4*)(n.W2s + k * 64 + tx * 8 + 4);
#pragma unroll
        for (int i = 0; i < 2; ++i) {
            float xv = n.xs[ty * 2 + i][k];
            float xq = xv * xv;
            acc1[i][0] = fmaf(xv, wa0.x, acc1[i][0]);
            acc1[i][1] = fmaf(xv, wa0.y, acc1[i][1]);
            acc1[i][2] = fmaf(xv, wa0.z, acc1[i][2]);
            acc1[i][3] = fmaf(xv, wa0.w, acc1[i][3]);
            acc1[i][4] = fmaf(xv, wa1.x, acc1[i][4]);
            acc1[i][5] = fmaf(xv, wa1.y, acc1[i][5]);
            acc1[i][6] = fmaf(xv, wa1.z, acc1[i][6]);
            acc1[i][7] = fmaf(xv, wa1.w, acc1[i][7]);
            acc2[i][0] = fmaf(xq, wb0.x, acc2[i][0]);
            acc2[i][1] = fmaf(xq, wb0.y, acc2[i][1]);
            acc2[i][2] = fmaf(xq, wb0.z, acc2[i][2]);
            acc2[i][3] = fmaf(xq, wb0.w, acc2[i][3]);
            acc2[i][4] = fmaf(xq, wb1.x, acc2[i][4]);
            acc2[i][5] = fmaf(xq, wb1.y, acc2[i][5]);
            acc2[i][6] = fmaf(xq, wb1.z, acc2[i][6]);
            acc2[i][7] = fmaf(xq, wb1.w, acc2[i][7]);
        }
    }
    float bv[8];
#pragma unroll
    for (int j = 0; j < 8; ++j) bv[j] = n.bs[tx * 8 + j];
#pragma unroll
    for (int i = 0; i < 2; ++i) {
        int node = base + ty * 2 + i;
        if (node < n_nodes) {
            float z[8];
            unsigned pk[4];
#pragma unroll
            for (int j = 0; j < 4; ++j) {
                float ylo = acc1[i][2 * j]     + acc2[i][2 * j];
                float yhi = acc1[i][2 * j + 1] + acc2[i][2 * j + 1];
                pk[j] = (unsigned)f2bf(ylo) | ((unsigned)f2bf(yhi) << 16);
            }
#pragma unroll
            for (int j = 0; j < 8; ++j) z[j] = acc1[i][j] + bv[j];
            unsigned short* yp = Yb + (size_t)node * 64 + tx * 8;
            float* zp = Z + (size_t)node * 64 + tx * 8;
            *(uint4*)(yp) = make_uint4(pk[0], pk[1], pk[2], pk[3]);
            *(float4*)(zp)     = make_float4(z[0], z[1], z[2], z[3]);
            *(float4*)(zp + 4) = make_float4(z[4], z[5], z[6], z[7]);
        }
    }
}

__global__ __launch_bounds__(256) void edge_scatter(
    const int* __restrict__ rows, const int* __restrict__ cols,
    const float* __restrict__ vals, const unsigned short* __restrict__ Yb,
    float* __restrict__ out, int n_edges)
{
    int t = blockIdx.x * 256 + threadIdx.x;
    int e = t >> 4;
    int f = (t & 15) << 2;
    if (e >= n_edges) return;
    int r = rows[e];
    int c = cols[e];
    float v = vals[e];
    const unsigned short* y = Yb + (size_t)c * 64 + f;
    float* o = out + (size_t)r * 64 + f;
    atomicAdd(o + 0, v * bf2f(y[0]));
    atomicAdd(o + 1, v * bf2f(y[1]));
    atomicAdd(o + 2, v * bf2f(y[2]));
    atomicAdd(o + 3, v * bf2f(y[3]));
}

extern "C" void kernel_launch(void* const* d_in, const int* in_sizes, int n_in,
                              void* d_out, int out_size, void* d_ws, size_t ws_size,
                              hipStream_t stream) {
    const int*   rows = (const int*)d_in[0];
    const int*   cols = (const int*)d_in[1];
    const float* vals = (const float*)d_in[2];
    const float* X    = (const float*)d_in[3];
    const float* W1   = (const float*)d_in[4];
    const float* b1   = (const float*)d_in[5];
    const float* W2   = (const float*)d_in[6];
    const float* b2   = (const float*)d_in[7];
    float* out = (float*)d_out;

    const int n_edges = in_sizes[0];
    const int n_nodes = in_sizes[3] / 64;
    const int nbuck = (n_nodes + ROWS_PER_BUCKET - 1) / ROWS_PER_BUCKET;

    char* ws = (char*)d_ws;
    size_t o_Yb     = 0;                                    // bf16 Y
    size_t o_packed = o_Yb + (size_t)n_nodes * 64 * 2;      // 16B-aligned (n*128)
    size_t o_ovf    = o_packed + (size_t)NBUCK_PAD * CAP * 8;
    size_t o_gcurs  = o_ovf + (size_t)OVF_CAP * 16;
    size_t o_ovfcnt = o_gcurs + NBUCK_PAD * 4;
    size_t need     = o_ovfcnt + 16;

    unsigned short* Yb = (unsigned short*)(ws + o_Yb);

    const int nb_nt = (n_nodes + NT_ROWS - 1) / NT_ROWS;

    if (ws_size >= need && nbuck <= NBUCK_PAD && n_nodes <= (1 << COL_BITS)) {
        int2* packed  = (int2*)(ws + o_packed);
        int4* ovf     = (int4*)(ws + o_ovf);
        int*  gcursor = (int*)(ws + o_gcurs);
        int*  ovfcnt  = (int*)(ws + o_ovfcnt);

        int eb = (n_edges + CHUNK - 1) / CHUNK;

        cursor_init<<<(NBUCK_PAD + 255) / 256, 256, 0, stream>>>(gcursor, ovfcnt, NBUCK_PAD);
        fused_nt_bin<<<eb + nb_nt, 256, 0, stream>>>(
            X, W1, b1, W2, b2, Yb, out, rows, cols, vals,
            gcursor, packed, ovfcnt, ovf, n_nodes, n_edges, eb);
        bucket_gather_half<<<nbuck * 2, 256, 0, stream>>>(
            gcursor, packed, Yb, out, ovfcnt, ovf, n_nodes);
    } else {
        node_transform_fb<<<nb_nt, 256, 0, stream>>>(X, W1, b1, W2, b2, Yb, out, n_nodes);
        long long threads = (long long)n_edges * 16;
        int eblocks = (int)((threads + 255) / 256);
        edge_scatter<<<eblocks, 256, 0, stream>>>(rows, cols, vals, Yb, out, n_edges);
    }
}

// Round 10
// 220.148 us; speedup vs baseline: 1.0079x; 1.0079x over previous
//
#include <hip/hip_runtime.h>

// out = L@(X@W1 + X^2@W2) + X@W1 + b1 + b2
// Y (bf16, ws) = X@W1 + X^2@W2 ; Z = X@W1 + b1 + b2 (-> out).
// Round 10: fused_nt_bin with KSTEP=32 (2 staging rounds; NtSmem ~33 KB ==
// ScatterSmem -> union 33 KB -> 4 blocks/CU). Gather = r7's proven
// feature-half kernel (58 us) with overflow drain folded in. 3 dispatches.

#define ROWS_PER_BUCKET 128
#define ROW_SHIFT 7
#define NBUCK_PAD 784        // 196*4, covers nbuck=782
#define SCAN_T 196
#define CAP 2048             // per-bucket fixed capacity (mean 1536, +13 sigma)
#define CHUNK 2048           // edges per scatter-role block
#define NT_ROWS 64           // rows per transform-role block
#define KSTEP 32             // k-slice of W staged at a time (2 rounds)
#define MAXB 2048
#define COL_BITS 17
#define COL_MASK 0x1FFFF
#define OVF_CAP 65536

__device__ __forceinline__ unsigned short f2bf(float x) {
    unsigned u = __float_as_uint(x);
    unsigned r = (u + 0x7FFFu + ((u >> 16) & 1u)) >> 16;   // RNE
    return (unsigned short)r;
}
__device__ __forceinline__ float bf2f(unsigned short h) {
    return __uint_as_float(((unsigned)h) << 16);
}

struct ScatterSmem {                 // ~33 KB
    int lcount[NBUCK_PAD];
    int lstart[NBUCK_PAD];
    int lcursor[NBUCK_PAD];
    int gbase[NBUCK_PAD];
    int sx[CHUNK];
    int sy[CHUNK];
    unsigned short sbk[CHUNK];
};
struct NtSmem {                      // 16 KB W slices + 16.6 KB xs + bs ~= 33 KB
    float W1s[KSTEP * 64];
    float W2s[KSTEP * 64];
    float xs[NT_ROWS][65];
    float bs[64];
};
union FusedSmem { ScatterSmem s; NtSmem n; };

__global__ __launch_bounds__(256) void cursor_init(
    int* __restrict__ gcursor, int* __restrict__ ovf_count, int nbp) {
    int i = blockIdx.x * 256 + threadIdx.x;
    if (i < nbp) gcursor[i] = i * CAP;
    if (i == 0) *ovf_count = 0;
}

__global__ __launch_bounds__(256) void fused_nt_bin(
    const float* __restrict__ X, const float* __restrict__ W1,
    const float* __restrict__ b1, const float* __restrict__ W2,
    const float* __restrict__ b2, unsigned short* __restrict__ Yb,
    float* __restrict__ Z,
    const int* __restrict__ rows, const int* __restrict__ cols,
    const float* __restrict__ vals, int* __restrict__ gcursor,
    int2* __restrict__ packed, int* __restrict__ ovf_count,
    int4* __restrict__ ovf, int n_nodes, int n_edges, int eb)
{
    __shared__ FusedSmem u;
    const int tid = threadIdx.x;

    if ((int)blockIdx.x < eb) {
        // ---------------- scatter role ----------------
        int eb0 = blockIdx.x * CHUNK;
        int cnt = min(CHUNK, n_edges - eb0);

        for (int k = tid; k < NBUCK_PAD; k += 256) u.s.lcount[k] = 0;
        __syncthreads();

        for (int i = tid; i < cnt; i += 256)
            atomicAdd(&u.s.lcount[rows[eb0 + i] >> ROW_SHIFT], 1);
        __syncthreads();

        // exclusive scan of lcount: thread t<SCAN_T owns 4t..4t+3
        int c0 = 0, c1 = 0, c2 = 0, c3 = 0, psum = 0;
        if (tid < SCAN_T) {
            c0 = u.s.lcount[tid * 4 + 0]; c1 = u.s.lcount[tid * 4 + 1];
            c2 = u.s.lcount[tid * 4 + 2]; c3 = u.s.lcount[tid * 4 + 3];
            psum = c0 + c1 + c2 + c3;
        }
        u.s.sx[tid] = psum;
        __syncthreads();
#pragma unroll
        for (int o = 1; o < 256; o <<= 1) {
            int t = (tid >= o) ? u.s.sx[tid - o] : 0;
            __syncthreads();
            u.s.sx[tid] += t;
            __syncthreads();
        }
        int base0 = u.s.sx[tid] - psum;
        __syncthreads();
        if (tid < SCAN_T) {
            u.s.lstart[tid * 4 + 0] = base0;
            u.s.lstart[tid * 4 + 1] = base0 + c0;
            u.s.lstart[tid * 4 + 2] = base0 + c0 + c1;
            u.s.lstart[tid * 4 + 3] = base0 + c0 + c1 + c2;
        }
        __syncthreads();

        for (int k = tid; k < NBUCK_PAD; k += 256) {
            u.s.lcursor[k] = u.s.lstart[k];
            if (u.s.lcount[k] > 0)
                u.s.gbase[k] = atomicAdd(&gcursor[k], u.s.lcount[k]);
        }
        __syncthreads();

        for (int i = tid; i < cnt; i += 256) {
            int r = rows[eb0 + i];
            int b = r >> ROW_SHIFT;
            int p = atomicAdd(&u.s.lcursor[b], 1);
            u.s.sx[p] = ((r & (ROWS_PER_BUCKET - 1)) << COL_BITS) | cols[eb0 + i];
            u.s.sy[p] = __float_as_int(vals[eb0 + i]);
            u.s.sbk[p] = (unsigned short)b;
        }
        __syncthreads();

        for (int i = tid; i < cnt; i += 256) {
            int b = u.s.sbk[i];
            int dest = u.s.gbase[b] + (i - u.s.lstart[b]);
            if (dest < (b + 1) * CAP) {
                packed[dest] = make_int2(u.s.sx[i], u.s.sy[i]);
            } else {
                int p = atomicAdd(ovf_count, 1);
                if (p < OVF_CAP)
                    ovf[p] = make_int4(
                        b * ROWS_PER_BUCKET + (u.s.sx[i] >> COL_BITS),
                        u.s.sx[i] & COL_MASK, u.s.sy[i], 0);
            }
        }
    } else {
        // ------- transform role (64-row tile, W staged in 2 k-slices) -------
        const int base = (blockIdx.x - eb) * NT_ROWS;

        if (tid < 64) u.n.bs[tid] = b1[tid] + b2[tid];
        {
#pragma unroll
            for (int i = 0; i < 4; ++i) {
                int idx = (tid + 256 * i) * 4;
                int r = idx >> 6, c = idx & 63;
                if (base + r < n_nodes) {
                    float4 v = *(const float4*)(X + (size_t)base * 64 + idx);
                    u.n.xs[r][c + 0] = v.x; u.n.xs[r][c + 1] = v.y;
                    u.n.xs[r][c + 2] = v.z; u.n.xs[r][c + 3] = v.w;
                }
            }
        }

        const int tx = tid & 7;    // features 8*tx..8*tx+7
        const int ty = tid >> 3;   // rows 2*ty, 2*ty+1

        float acc1[2][8] = {};
        float acc2[2][8] = {};

#pragma unroll
        for (int ks = 0; ks < 64; ks += KSTEP) {
            __syncthreads();   // first pass also covers xs/bs staging
            // stage W slice: KSTEP*64 floats each = 512 float4 -> 2/thread
            {
                const float4* w1v = (const float4*)(W1 + ks * 64);
                const float4* w2v = (const float4*)(W2 + ks * 64);
                ((float4*)u.n.W1s)[tid]       = w1v[tid];
                ((float4*)u.n.W1s)[tid + 256] = w1v[tid + 256];
                ((float4*)u.n.W2s)[tid]       = w2v[tid];
                ((float4*)u.n.W2s)[tid + 256] = w2v[tid + 256];
            }
            __syncthreads();

#pragma unroll 4
            for (int kk = 0; kk < KSTEP; ++kk) {
                float4 wa0 = *(const float4*)(u.n.W1s + kk * 64 + tx * 8);
                float4 wa1 = *(const float4*)(u.n.W1s + kk * 64 + tx * 8 + 4);
                float4 wb0 = *(const float4*)(u.n.W2s + kk * 64 + tx * 8);
                float4 wb1 = *(const float4*)(u.n.W2s + kk * 64 + tx * 8 + 4);
#pragma unroll
                for (int i = 0; i < 2; ++i) {
                    float xv = u.n.xs[ty * 2 + i][ks + kk];
                    float xq = xv * xv;
                    acc1[i][0] = fmaf(xv, wa0.x, acc1[i][0]);
                    acc1[i][1] = fmaf(xv, wa0.y, acc1[i][1]);
                    acc1[i][2] = fmaf(xv, wa0.z, acc1[i][2]);
                    acc1[i][3] = fmaf(xv, wa0.w, acc1[i][3]);
                    acc1[i][4] = fmaf(xv, wa1.x, acc1[i][4]);
                    acc1[i][5] = fmaf(xv, wa1.y, acc1[i][5]);
                    acc1[i][6] = fmaf(xv, wa1.z, acc1[i][6]);
                    acc1[i][7] = fmaf(xv, wa1.w, acc1[i][7]);
                    acc2[i][0] = fmaf(xq, wb0.x, acc2[i][0]);
                    acc2[i][1] = fmaf(xq, wb0.y, acc2[i][1]);
                    acc2[i][2] = fmaf(xq, wb0.z, acc2[i][2]);
                    acc2[i][3] = fmaf(xq, wb0.w, acc2[i][3]);
                    acc2[i][4] = fmaf(xq, wb1.x, acc2[i][4]);
                    acc2[i][5] = fmaf(xq, wb1.y, acc2[i][5]);
                    acc2[i][6] = fmaf(xq, wb1.z, acc2[i][6]);
                    acc2[i][7] = fmaf(xq, wb1.w, acc2[i][7]);
                }
            }
        }

        float bv[8];
#pragma unroll
        for (int j = 0; j < 8; ++j) bv[j] = u.n.bs[tx * 8 + j];

#pragma unroll
        for (int i = 0; i < 2; ++i) {
            int node = base + ty * 2 + i;
            if (node < n_nodes) {
                float z[8];
                unsigned pk[4];
#pragma unroll
                for (int j = 0; j < 4; ++j) {
                    float ylo = acc1[i][2 * j]     + acc2[i][2 * j];
                    float yhi = acc1[i][2 * j + 1] + acc2[i][2 * j + 1];
                    pk[j] = (unsigned)f2bf(ylo) | ((unsigned)f2bf(yhi) << 16);
                }
#pragma unroll
                for (int j = 0; j < 8; ++j) z[j] = acc1[i][j] + bv[j];
                unsigned short* yp = Yb + (size_t)node * 64 + tx * 8;
                float* zp = Z + (size_t)node * 64 + tx * 8;
                *(uint4*)(yp) = make_uint4(pk[0], pk[1], pk[2], pk[3]);
                *(float4*)(zp)     = make_float4(z[0], z[1], z[2], z[3]);
                *(float4*)(zp + 4) = make_float4(z[4], z[5], z[6], z[7]);
            }
        }
    }
}

// 2 blocks per bucket (feature halves) — r7's proven kernel. In-LDS counting
// sort by local row, then register-accumulated gather from bf16 Y, coalesced
// out+= per row. Overflow drain folded in at the end.
__global__ __launch_bounds__(256) void bucket_gather_split(
    const int* __restrict__ gcursor, const int2* __restrict__ packed,
    const unsigned short* __restrict__ Yb, float* __restrict__ out,
    const int* __restrict__ ovf_count, const int4* __restrict__ ovf,
    int n_nodes) {
    __shared__ int2 sxy[MAXB];                     // 16 KB
    __shared__ unsigned short dsti[MAXB];          // 4 KB
    __shared__ int hist[ROWS_PER_BUCKET];
    __shared__ int chs[ROWS_PER_BUCKET];
    __shared__ int chc[ROWS_PER_BUCKET];

    int tid = threadIdx.x;
    int bucket = blockIdx.x >> 1;
    int fcol = ((blockIdx.x & 1) * 32) + (tid & 31);
    int rowlane = tid >> 5;        // 0..7
    int s = bucket * CAP;
    int e = min(gcursor[bucket], s + CAP);
    int cnt = e - s;
    int row0 = bucket * ROWS_PER_BUCKET;

    if (tid < ROWS_PER_BUCKET) hist[tid] = 0;
    __syncthreads();

    for (int i = tid; i < cnt; i += 256) {
        int2 a = packed[s + i];
        sxy[i] = a;
        atomicAdd(&hist[a.x >> COL_BITS], 1);
    }
    __syncthreads();

    if (tid < ROWS_PER_BUCKET) chs[tid] = hist[tid];
    __syncthreads();
#pragma unroll
    for (int o = 1; o < ROWS_PER_BUCKET; o <<= 1) {
        int t = 0;
        if (tid < ROWS_PER_BUCKET && tid >= o) t = chs[tid - o];
        __syncthreads();
        if (tid < ROWS_PER_BUCKET) chs[tid] += t;
        __syncthreads();
    }
    if (tid < ROWS_PER_BUCKET) {
        int excl = chs[tid] - hist[tid];
        chs[tid] = excl;
        chc[tid] = excl;
    }
    __syncthreads();

    for (int i = tid; i < cnt; i += 256) {
        int r = sxy[i].x >> COL_BITS;
        int p = atomicAdd(&chc[r], 1);
        dsti[p] = (unsigned short)i;
    }
    __syncthreads();

    for (int rr = 0; rr < 16; ++rr) {
        int r = rowlane * 16 + rr;
        int rc = hist[r];
        int node = row0 + r;
        if (rc == 0 || node >= n_nodes) continue;
        int rs = chs[r];
        float acc = 0.f;
        int j = 0;
        for (; j + 8 <= rc; j += 8) {
            int i0 = dsti[rs + j + 0], i1 = dsti[rs + j + 1];
            int i2 = dsti[rs + j + 2], i3 = dsti[rs + j + 3];
            int i4 = dsti[rs + j + 4], i5 = dsti[rs + j + 5];
            int i6 = dsti[rs + j + 6], i7 = dsti[rs + j + 7];
            int2 a0 = sxy[i0], a1 = sxy[i1], a2 = sxy[i2], a3 = sxy[i3];
            int2 a4 = sxy[i4], a5 = sxy[i5], a6 = sxy[i6], a7 = sxy[i7];
            float f0 = bf2f(Yb[(size_t)(a0.x & COL_MASK) * 64 + fcol]);
            float f1 = bf2f(Yb[(size_t)(a1.x & COL_MASK) * 64 + fcol]);
            float f2 = bf2f(Yb[(size_t)(a2.x & COL_MASK) * 64 + fcol]);
            float f3 = bf2f(Yb[(size_t)(a3.x & COL_MASK) * 64 + fcol]);
            float f4 = bf2f(Yb[(size_t)(a4.x & COL_MASK) * 64 + fcol]);
            float f5 = bf2f(Yb[(size_t)(a5.x & COL_MASK) * 64 + fcol]);
            float f6 = bf2f(Yb[(size_t)(a6.x & COL_MASK) * 64 + fcol]);
            float f7 = bf2f(Yb[(size_t)(a7.x & COL_MASK) * 64 + fcol]);
            acc = fmaf(__int_as_float(a0.y), f0, acc);
            acc = fmaf(__int_as_float(a1.y), f1, acc);
            acc = fmaf(__int_as_float(a2.y), f2, acc);
            acc = fmaf(__int_as_float(a3.y), f3, acc);
            acc = fmaf(__int_as_float(a4.y), f4, acc);
            acc = fmaf(__int_as_float(a5.y), f5, acc);
            acc = fmaf(__int_as_float(a6.y), f6, acc);
            acc = fmaf(__int_as_float(a7.y), f7, acc);
        }
        for (; j + 4 <= rc; j += 4) {
            int i0 = dsti[rs + j + 0], i1 = dsti[rs + j + 1];
            int i2 = dsti[rs + j + 2], i3 = dsti[rs + j + 3];
            int2 a0 = sxy[i0], a1 = sxy[i1], a2 = sxy[i2], a3 = sxy[i3];
            float f0 = bf2f(Yb[(size_t)(a0.x & COL_MASK) * 64 + fcol]);
            float f1 = bf2f(Yb[(size_t)(a1.x & COL_MASK) * 64 + fcol]);
            float f2 = bf2f(Yb[(size_t)(a2.x & COL_MASK) * 64 + fcol]);
            float f3 = bf2f(Yb[(size_t)(a3.x & COL_MASK) * 64 + fcol]);
            acc = fmaf(__int_as_float(a0.y), f0, acc);
            acc = fmaf(__int_as_float(a1.y), f1, acc);
            acc = fmaf(__int_as_float(a2.y), f2, acc);
            acc = fmaf(__int_as_float(a3.y), f3, acc);
        }
        for (; j < rc; ++j) {
            int i0 = dsti[rs + j];
            int2 a0 = sxy[i0];
            acc = fmaf(__int_as_float(a0.y),
                       bf2f(Yb[(size_t)(a0.x & COL_MASK) * 64 + fcol]), acc);
        }
        out[(size_t)node * 64 + fcol] += acc;   // out holds Z
    }

    // overflow drain (normally empty)
    int oc = min(*ovf_count, OVF_CAP);
    if (oc > 0) {
        long long total = (long long)oc * 64;
        for (long long i = (long long)blockIdx.x * 256 + tid; i < total;
             i += (long long)gridDim.x * 256) {
            int ee = (int)(i >> 6), f = (int)(i & 63);
            int4 a = ovf[ee];
            atomicAdd(&out[(size_t)a.x * 64 + f],
                      __int_as_float(a.z) * bf2f(Yb[(size_t)a.y * 64 + f]));
        }
    }
}

// ---------------- fallback path ----------------

struct FbSmem {
    float W1s[64 * 64];
    float W2s[64 * 64];
    float xs[NT_ROWS][65];
    float bs[64];
};

__global__ __launch_bounds__(256) void node_transform_fb(
    const float* __restrict__ X, const float* __restrict__ W1,
    const float* __restrict__ b1, const float* __restrict__ W2,
    const float* __restrict__ b2, unsigned short* __restrict__ Yb,
    float* __restrict__ Z, int n_nodes)
{
    __shared__ FbSmem n;
    const int tid = threadIdx.x;
    const int base = blockIdx.x * NT_ROWS;
    {
        const float4* w1v = (const float4*)W1;
        const float4* w2v = (const float4*)W2;
        float4* s1 = (float4*)n.W1s;
        float4* s2 = (float4*)n.W2s;
#pragma unroll
        for (int i = 0; i < 4; ++i) {
            s1[tid + 256 * i] = w1v[tid + 256 * i];
            s2[tid + 256 * i] = w2v[tid + 256 * i];
        }
    }
    if (tid < 64) n.bs[tid] = b1[tid] + b2[tid];
#pragma unroll
    for (int i = 0; i < 4; ++i) {
        int idx = (tid + 256 * i) * 4;
        int r = idx >> 6, c = idx & 63;
        if (base + r < n_nodes) {
            float4 v = *(const float4*)(X + (size_t)base * 64 + idx);
            n.xs[r][c + 0] = v.x; n.xs[r][c + 1] = v.y;
            n.xs[r][c + 2] = v.z; n.xs[r][c + 3] = v.w;
        }
    }
    __syncthreads();
    const int tx = tid & 7;
    const int ty = tid >> 3;
    float acc1[2][8] = {};
    float acc2[2][8] = {};
#pragma unroll 2
    for (int k = 0; k < 64; ++k) {
        float4 wa0 = *(const float4*)(n.W1s + k * 64 + tx * 8);
        float4 wa1 = *(const float4*)(n.W1s + k * 64 + tx * 8 + 4);
        float4 wb0 = *(const float4*)(n.W2s + k * 64 + tx * 8);
        float4 wb1 = *(const float4*)(n.W2s + k * 64 + tx * 8 + 4);
#pragma unroll
        for (int i = 0; i < 2; ++i) {
            float xv = n.xs[ty * 2 + i][k];
            float xq = xv * xv;
            acc1[i][0] = fmaf(xv, wa0.x, acc1[i][0]);
            acc1[i][1] = fmaf(xv, wa0.y, acc1[i][1]);
            acc1[i][2] = fmaf(xv, wa0.z, acc1[i][2]);
            acc1[i][3] = fmaf(xv, wa0.w, acc1[i][3]);
            acc1[i][4] = fmaf(xv, wa1.x, acc1[i][4]);
            acc1[i][5] = fmaf(xv, wa1.y, acc1[i][5]);
            acc1[i][6] = fmaf(xv, wa1.z, acc1[i][6]);
            acc1[i][7] = fmaf(xv, wa1.w, acc1[i][7]);
            acc2[i][0] = fmaf(xq, wb0.x, acc2[i][0]);
            acc2[i][1] = fmaf(xq, wb0.y, acc2[i][1]);
            acc2[i][2] = fmaf(xq, wb0.z, acc2[i][2]);
            acc2[i][3] = fmaf(xq, wb0.w, acc2[i][3]);
            acc2[i][4] = fmaf(xq, wb1.x, acc2[i][4]);
            acc2[i][5] = fmaf(xq, wb1.y, acc2[i][5]);
            acc2[i][6] = fmaf(xq, wb1.z, acc2[i][6]);
            acc2[i][7] = fmaf(xq, wb1.w, acc2[i][7]);
        }
    }
    float bv[8];
#pragma unroll
    for (int j = 0; j < 8; ++j) bv[j] = n.bs[tx * 8 + j];
#pragma unroll
    for (int i = 0; i < 2; ++i) {
        int node = base + ty * 2 + i;
        if (node < n_nodes) {
            float z[8];
            unsigned pk[4];
#pragma unroll
            for (int j = 0; j < 4; ++j) {
                float ylo = acc1[i][2 * j]     + acc2[i][2 * j];
                float yhi = acc1[i][2 * j + 1] + acc2[i][2 * j + 1];
                pk[j] = (unsigned)f2bf(ylo) | ((unsigned)f2bf(yhi) << 16);
            }
#pragma unroll
            for (int j = 0; j < 8; ++j) z[j] = acc1[i][j] + bv[j];
            unsigned short* yp = Yb + (size_t)node * 64 + tx * 8;
            float* zp = Z + (size_t)node * 64 + tx * 8;
            *(uint4*)(yp) = make_uint4(pk[0], pk[1], pk[2], pk[3]);
            *(float4*)(zp)     = make_float4(z[0], z[1], z[2], z[3]);
            *(float4*)(zp + 4) = make_float4(z[4], z[5], z[6], z[7]);
        }
    }
}

__global__ __launch_bounds__(256) void edge_scatter(
    const int* __restrict__ rows, const int* __restrict__ cols,
    const float* __restrict__ vals, const unsigned short* __restrict__ Yb,
    float* __restrict__ out, int n_edges)
{
    int t = blockIdx.x * 256 + threadIdx.x;
    int e = t >> 4;
    int f = (t & 15) << 2;
    if (e >= n_edges) return;
    int r = rows[e];
    int c = cols[e];
    float v = vals[e];
    const unsigned short* y = Yb + (size_t)c * 64 + f;
    float* o = out + (size_t)r * 64 + f;
    atomicAdd(o + 0, v * bf2f(y[0]));
    atomicAdd(o + 1, v * bf2f(y[1]));
    atomicAdd(o + 2, v * bf2f(y[2]));
    atomicAdd(o + 3, v * bf2f(y[3]));
}

extern "C" void kernel_launch(void* const* d_in, const int* in_sizes, int n_in,
                              void* d_out, int out_size, void* d_ws, size_t ws_size,
                              hipStream_t stream) {
    const int*   rows = (const int*)d_in[0];
    const int*   cols = (const int*)d_in[1];
    const float* vals = (const float*)d_in[2];
    const float* X    = (const float*)d_in[3];
    const float* W1   = (const float*)d_in[4];
    const float* b1   = (const float*)d_in[5];
    const float* W2   = (const float*)d_in[6];
    const float* b2   = (const float*)d_in[7];
    float* out = (float*)d_out;

    const int n_edges = in_sizes[0];
    const int n_nodes = in_sizes[3] / 64;
    const int nbuck = (n_nodes + ROWS_PER_BUCKET - 1) / ROWS_PER_BUCKET;

    char* ws = (char*)d_ws;
    size_t o_Yb     = 0;                                    // bf16 Y
    size_t o_packed = o_Yb + (size_t)n_nodes * 64 * 2;      // 16B-aligned (n*128)
    size_t o_ovf    = o_packed + (size_t)NBUCK_PAD * CAP * 8;
    size_t o_gcurs  = o_ovf + (size_t)OVF_CAP * 16;
    size_t o_ovfcnt = o_gcurs + NBUCK_PAD * 4;
    size_t need     = o_ovfcnt + 16;

    unsigned short* Yb = (unsigned short*)(ws + o_Yb);

    const int nb_nt = (n_nodes + NT_ROWS - 1) / NT_ROWS;

    if (ws_size >= need && nbuck <= NBUCK_PAD && n_nodes <= (1 << COL_BITS)) {
        int2* packed  = (int2*)(ws + o_packed);
        int4* ovf     = (int4*)(ws + o_ovf);
        int*  gcursor = (int*)(ws + o_gcurs);
        int*  ovfcnt  = (int*)(ws + o_ovfcnt);

        int eb = (n_edges + CHUNK - 1) / CHUNK;

        cursor_init<<<(NBUCK_PAD + 255) / 256, 256, 0, stream>>>(gcursor, ovfcnt, NBUCK_PAD);
        fused_nt_bin<<<eb + nb_nt, 256, 0, stream>>>(
            X, W1, b1, W2, b2, Yb, out, rows, cols, vals,
            gcursor, packed, ovfcnt, ovf, n_nodes, n_edges, eb);
        bucket_gather_split<<<nbuck * 2, 256, 0, stream>>>(
            gcursor, packed, Yb, out, ovfcnt, ovf, n_nodes);
    } else {
        node_transform_fb<<<nb_nt, 256, 0, stream>>>(X, W1, b1, W2, b2, Yb, out, n_nodes);
        long long threads = (long long)n_edges * 16;
        int eblocks = (int)((threads + 255) / 256);
        edge_scatter<<<eblocks, 256, 0, stream>>>(rows, cols, vals, Yb, out, n_edges);
    }
}